// Round 1
// baseline (732.578 us; speedup 1.0000x reference)
//
#include <hip/hip_runtime.h>

#define B_ 8
#define H_ 1024
#define N_ 64
#define L_ 4096

// ---------------------------------------------------------------------------
// Setup: Wt[h][n] = W[n][h]; CB[h][n] = C[h][n]*Bvec[n];
//        base[h] = sum_n C[h][n] * (A@Bvec)[n]
// grid: 16 blocks x 256 threads; block bi handles h-tile [bi*64, bi*64+64)
// ---------------------------------------------------------------------------
__global__ __launch_bounds__(256) void setup_kernel(
    const float* __restrict__ C,
    const float* __restrict__ Bvec,
    const float* __restrict__ A,
    const float* __restrict__ W,
    float* __restrict__ Wt,    // [H][N]
    float* __restrict__ CB,    // [H][N]
    float* __restrict__ base)  // [H]
{
    __shared__ float bv[64];
    __shared__ float abv[64];
    __shared__ float tile[64][65];
    const int tid = threadIdx.x;
    const int h0 = blockIdx.x * 64;

    if (tid < 64) bv[tid] = Bvec[tid];
    __syncthreads();

    if (tid < 64) {  // ABv (redundant per block, tiny)
        float s = 0.f;
        const float* Arow = A + tid * 64;
        #pragma unroll 8
        for (int m = 0; m < 64; ++m) s += Arow[m] * bv[m];
        abv[tid] = s;
    }

    // load W tile: rows n=0..63, cols h0..h0+63 (coalesced in h)
    #pragma unroll
    for (int k = 0; k < 16; ++k) {
        int j = tid + k * 256;
        int n = j >> 6, c = j & 63;
        tile[n][c] = W[n * H_ + h0 + c];
    }
    __syncthreads();

    // write Wt (coalesced in n) + CB
    #pragma unroll
    for (int k = 0; k < 16; ++k) {
        int j = tid + k * 256;
        int r = j >> 6, n = j & 63;
        Wt[(h0 + r) * 64 + n] = tile[n][r];
        float c = C[(h0 + r) * 64 + n];
        CB[(h0 + r) * 64 + n] = c * bv[n];
    }

    if (tid < 64) {
        float s = 0.f;
        const float* Crow = C + (h0 + tid) * 64;
        #pragma unroll 8
        for (int n = 0; n < 64; ++n) s += Crow[n] * abv[n];
        base[h0 + tid] = s;
    }
}

// ---------------------------------------------------------------------------
// dA[b][n][l] = sum_h du[b][h][l] * Wt[h][n]
// grid: (64 l-tiles, 8 b) x 256 threads. Wave w covers h in [w*256,(w+1)*256);
// lane <-> l within a 64-wide l tile. 4-way LDS reduce across waves.
// ---------------------------------------------------------------------------
__global__ __launch_bounds__(256) void dA_kernel(
    const float* __restrict__ du,  // [B][H][L]
    const float* __restrict__ Wt,  // [H][N]
    float* __restrict__ dA)        // [B][N][L]
{
    __shared__ float red[4][64][64];  // 64 KB
    const int tid  = threadIdx.x;
    const int lane = tid & 63;
    const int w    = tid >> 6;
    const int t    = blockIdx.x;
    const int b    = blockIdx.y;
    const int l    = t * 64 + lane;

    float acc[64];
    #pragma unroll
    for (int n = 0; n < 64; ++n) acc[n] = 0.f;

    const float* dup = du + ((size_t)b * H_ + (size_t)w * 256) * L_ + l;
    const float* wtp = Wt + (w * 256) * 64;
    for (int h = 0; h < 256; ++h) {
        float d = dup[(size_t)h * L_];
        const float* wr = wtp + h * 64;
        #pragma unroll
        for (int n = 0; n < 64; ++n) acc[n] = fmaf(d, wr[n], acc[n]);
    }

    #pragma unroll
    for (int n = 0; n < 64; ++n) red[w][n][lane] = acc[n];
    __syncthreads();

    float* out = dA + (size_t)b * N_ * L_ + t * 64;
    #pragma unroll
    for (int k = 0; k < 16; ++k) {
        int j  = tid + k * 256;   // 0..4095 : n = j>>6, l' = j&63
        int n  = j >> 6;
        int ll = j & 63;
        float s = red[0][n][ll] + red[1][n][ll] + red[2][n][ll] + red[3][n][ll];
        out[(size_t)n * L_ + ll] = s;
    }
}

// ---------------------------------------------------------------------------
// In-place inclusive cumsum over l for each (b,n) row of S (= dA buffer).
// grid: (64 n, 8 b) x 256 threads; 16 elements/thread, reg scan + wave scan.
// ---------------------------------------------------------------------------
__global__ __launch_bounds__(256) void scan_kernel(float* __restrict__ S)
{
    const int n = blockIdx.x;
    const int b = blockIdx.y;
    float* row = S + (size_t)(b * 64 + n) * L_;
    const int tid  = threadIdx.x;
    const int lane = tid & 63;
    const int w    = tid >> 6;

    float v[16];
    const float4* rp = reinterpret_cast<const float4*>(row + tid * 16);
    #pragma unroll
    for (int q = 0; q < 4; ++q) {
        float4 a = rp[q];
        v[q * 4 + 0] = a.x; v[q * 4 + 1] = a.y;
        v[q * 4 + 2] = a.z; v[q * 4 + 3] = a.w;
    }

    float run = 0.f;
    #pragma unroll
    for (int i = 0; i < 16; ++i) { run += v[i]; v[i] = run; }
    const float tot = run;

    // wave inclusive scan of per-thread totals
    float sc = tot;
    #pragma unroll
    for (int d = 1; d < 64; d <<= 1) {
        float u = __shfl_up(sc, d);
        if (lane >= d) sc += u;
    }
    const float lane_excl = sc - tot;

    __shared__ float wtot[4];
    if (lane == 63) wtot[w] = sc;
    __syncthreads();
    float woff = 0.f;
    #pragma unroll
    for (int ww = 0; ww < 4; ++ww)
        if (ww < w) woff += wtot[ww];

    const float off = woff + lane_excl;
    float4* wp = reinterpret_cast<float4*>(row + tid * 16);
    #pragma unroll
    for (int q = 0; q < 4; ++q) {
        float4 a;
        a.x = v[q * 4 + 0] + off; a.y = v[q * 4 + 1] + off;
        a.z = v[q * 4 + 2] + off; a.w = v[q * 4 + 3] + off;
        wp[q] = a;
    }
}

// ---------------------------------------------------------------------------
// K[b][h][l] = base[h] + sum_n CB[h][n] * S[b][n][l]
// grid: (64 l-tiles, 8 b) x 256 threads. Wave w covers h stripe of 256;
// lane <-> l. S column (64 f32) held in VGPRs.
// ---------------------------------------------------------------------------
__global__ __launch_bounds__(256) void out_kernel(
    const float* __restrict__ S,     // [B][N][L]
    const float* __restrict__ CB,    // [H][N]
    const float* __restrict__ base,  // [H]
    float* __restrict__ K)           // [B][H][L]
{
    const int tid  = threadIdx.x;
    const int lane = tid & 63;
    const int w    = tid >> 6;
    const int t    = blockIdx.x;
    const int b    = blockIdx.y;
    const int l    = t * 64 + lane;

    float sv[64];
    const float* sp = S + (size_t)b * N_ * L_ + l;
    #pragma unroll
    for (int n = 0; n < 64; ++n) sv[n] = sp[(size_t)n * L_];

    float* kp = K + ((size_t)b * H_ + (size_t)w * 256) * L_ + l;
    const float* cbp = CB + (w * 256) * 64;
    const float* bp  = base + w * 256;
    for (int h = 0; h < 256; ++h) {
        float acc = bp[h];
        const float* cr = cbp + h * 64;
        #pragma unroll
        for (int n = 0; n < 64; ++n) acc = fmaf(cr[n], sv[n], acc);
        kp[(size_t)h * L_] = acc;
    }
}

// ---------------------------------------------------------------------------
extern "C" void kernel_launch(void* const* d_in, const int* in_sizes, int n_in,
                              void* d_out, int out_size, void* d_ws, size_t ws_size,
                              hipStream_t stream) {
    const float* du   = (const float*)d_in[0];  // [B][H][L]
    const float* C    = (const float*)d_in[1];  // [H][N]
    const float* Bvec = (const float*)d_in[2];  // [N]
    const float* A    = (const float*)d_in[3];  // [N][N]
    const float* W    = (const float*)d_in[4];  // [N][H]
    float* K = (float*)d_out;                   // [B][H][L]

    float* ws   = (float*)d_ws;
    float* S    = ws;                                  // B*N*L   = 2,097,152 f
    float* Wt   = ws + (size_t)B_ * N_ * L_;           // H*N     = 65,536 f
    float* CB   = Wt + (size_t)H_ * N_;                // H*N     = 65,536 f
    float* base = CB + (size_t)H_ * N_;                // H       = 1,024 f

    setup_kernel<<<16, 256, 0, stream>>>(C, Bvec, A, W, Wt, CB, base);
    dA_kernel<<<dim3(L_ / 64, B_), 256, 0, stream>>>(du, Wt, S);
    scan_kernel<<<dim3(N_, B_), 256, 0, stream>>>(S);
    out_kernel<<<dim3(L_ / 64, B_), 256, 0, stream>>>(S, CB, base, K);
}

// Round 2
// 521.451 us; speedup vs baseline: 1.4049x; 1.4049x over previous
//
#include <hip/hip_runtime.h>

#define B_ 8
#define H_ 1024
#define N_ 64
#define L_ 4096

// ---------------------------------------------------------------------------
// Setup: Wt[h][n] = W[n][h]; CB[h][n] = C[h][n]*Bvec[n];
//        base[h] = sum_n C[h][n] * (A@Bvec)[n]
// ---------------------------------------------------------------------------
__global__ __launch_bounds__(256) void setup_kernel(
    const float* __restrict__ C,
    const float* __restrict__ Bvec,
    const float* __restrict__ A,
    const float* __restrict__ W,
    float* __restrict__ Wt,    // [H][N]
    float* __restrict__ CB,    // [H][N]
    float* __restrict__ base)  // [H]
{
    __shared__ float bv[64];
    __shared__ float abv[64];
    __shared__ float tile[64][65];
    const int tid = threadIdx.x;
    const int h0 = blockIdx.x * 64;

    if (tid < 64) bv[tid] = Bvec[tid];
    __syncthreads();

    if (tid < 64) {  // A@Bvec (redundant per block, tiny)
        float s = 0.f;
        const float* Arow = A + tid * 64;
        #pragma unroll 8
        for (int m = 0; m < 64; ++m) s += Arow[m] * bv[m];
        abv[tid] = s;
    }

    #pragma unroll
    for (int k = 0; k < 16; ++k) {
        int j = tid + k * 256;
        int n = j >> 6, c = j & 63;
        tile[n][c] = W[n * H_ + h0 + c];
    }
    __syncthreads();

    #pragma unroll
    for (int k = 0; k < 16; ++k) {
        int j = tid + k * 256;
        int r = j >> 6, n = j & 63;
        Wt[(h0 + r) * 64 + n] = tile[n][r];
        float c = C[(h0 + r) * 64 + n];
        CB[(h0 + r) * 64 + n] = c * bv[n];
    }

    if (tid < 64) {
        float s = 0.f;
        const float* Crow = C + (h0 + tid) * 64;
        #pragma unroll 8
        for (int n = 0; n < 64; ++n) s += Crow[n] * abv[n];
        base[h0 + tid] = s;
    }
}

// ---------------------------------------------------------------------------
// dA[b][n][l] = sum_h du[b][h][l] * Wt[h][n]
// grid: (64 l-tiles, 8 b) x 512 threads (8 waves). Wave w owns h stripe of
// 128; lane <-> l. Wt rows read through a readfirstlane-uniform pointer so
// they become s_load (scalar pipe) instead of 64 per-lane vector loads.
// 8-way cross-wave reduce via 32KB LDS in 4 n-chunks.
// ---------------------------------------------------------------------------
__global__ __launch_bounds__(512) void dA_kernel(
    const float* __restrict__ du,  // [B][H][L]
    const float* __restrict__ Wt,  // [H][N]
    float* __restrict__ dA)        // [B][N][L]
{
    __shared__ float red[8][16][64];  // 32 KB
    const int tid  = threadIdx.x;
    const int lane = tid & 63;
    const int w    = tid >> 6;
    const int t    = blockIdx.x;
    const int b    = blockIdx.y;
    const int l    = t * 64 + lane;

    float acc[64];
    #pragma unroll
    for (int n = 0; n < 64; ++n) acc[n] = 0.f;

    const int hbase = __builtin_amdgcn_readfirstlane(w * 128);
    const float* dup = du + ((size_t)b * H_ + hbase) * L_ + l;
    const float* wtp = Wt + (size_t)hbase * 64;   // SGPR-uniform base

    #pragma unroll 2
    for (int h = 0; h < 128; ++h) {
        float d = dup[(size_t)h * L_];
        const float* wr = wtp + h * 64;           // uniform address -> s_load
        #pragma unroll
        for (int n = 0; n < 64; ++n) acc[n] = fmaf(d, wr[n], acc[n]);
    }

    float* out = dA + (size_t)b * N_ * L_ + (size_t)t * 64;
    #pragma unroll 1
    for (int c = 0; c < 4; ++c) {
        __syncthreads();
        #pragma unroll
        for (int i = 0; i < 16; ++i) red[w][i][lane] = acc[c * 16 + i];
        __syncthreads();
        #pragma unroll
        for (int k = 0; k < 2; ++k) {
            int j  = tid + k * 512;   // 0..1023 : nn = j>>6, ll = j&63
            int nn = j >> 6;
            int ll = j & 63;
            float s = red[0][nn][ll] + red[1][nn][ll] + red[2][nn][ll] +
                      red[3][nn][ll] + red[4][nn][ll] + red[5][nn][ll] +
                      red[6][nn][ll] + red[7][nn][ll];
            out[(size_t)(c * 16 + nn) * L_ + ll] = s;
        }
    }
}

// ---------------------------------------------------------------------------
// In-place inclusive cumsum over l for each (b,n) row of S.
// ---------------------------------------------------------------------------
__global__ __launch_bounds__(256) void scan_kernel(float* __restrict__ S)
{
    const int n = blockIdx.x;
    const int b = blockIdx.y;
    float* row = S + (size_t)(b * 64 + n) * L_;
    const int tid  = threadIdx.x;
    const int lane = tid & 63;
    const int w    = tid >> 6;

    float v[16];
    const float4* rp = reinterpret_cast<const float4*>(row + tid * 16);
    #pragma unroll
    for (int q = 0; q < 4; ++q) {
        float4 a = rp[q];
        v[q * 4 + 0] = a.x; v[q * 4 + 1] = a.y;
        v[q * 4 + 2] = a.z; v[q * 4 + 3] = a.w;
    }

    float run = 0.f;
    #pragma unroll
    for (int i = 0; i < 16; ++i) { run += v[i]; v[i] = run; }
    const float tot = run;

    float sc = tot;
    #pragma unroll
    for (int d = 1; d < 64; d <<= 1) {
        float u = __shfl_up(sc, d);
        if (lane >= d) sc += u;
    }
    const float lane_excl = sc - tot;

    __shared__ float wtot[4];
    if (lane == 63) wtot[w] = sc;
    __syncthreads();
    float woff = 0.f;
    #pragma unroll
    for (int ww = 0; ww < 4; ++ww)
        if (ww < w) woff += wtot[ww];

    const float off = woff + lane_excl;
    float4* wp = reinterpret_cast<float4*>(row + tid * 16);
    #pragma unroll
    for (int q = 0; q < 4; ++q) {
        float4 a;
        a.x = v[q * 4 + 0] + off; a.y = v[q * 4 + 1] + off;
        a.z = v[q * 4 + 2] + off; a.w = v[q * 4 + 3] + off;
        wp[q] = a;
    }
}

// ---------------------------------------------------------------------------
// K[b][h][l] = base[h] + sum_n CB[h][n] * S[b][n][l]
// grid: (64 l-tiles, 8 b) x 512 threads (8 waves). Wave w owns h stripe of
// 128; lane <-> l. S column (64 f32) in VGPRs; CB rows via uniform pointer
// -> s_load on the scalar pipe; FMA = v_fmac(vgpr, sgpr, vgpr).
// ---------------------------------------------------------------------------
__global__ __launch_bounds__(512) void out_kernel(
    const float* __restrict__ S,     // [B][N][L]
    const float* __restrict__ CB,    // [H][N]
    const float* __restrict__ base,  // [H]
    float* __restrict__ K)           // [B][H][L]
{
    const int tid  = threadIdx.x;
    const int lane = tid & 63;
    const int w    = tid >> 6;
    const int t    = blockIdx.x;
    const int b    = blockIdx.y;
    const int l    = t * 64 + lane;

    float sv[64];
    const float* sp = S + (size_t)b * N_ * L_ + l;
    #pragma unroll
    for (int n = 0; n < 64; ++n) sv[n] = sp[(size_t)n * L_];

    const int hbase = __builtin_amdgcn_readfirstlane(w * 128);
    const float* cbp = CB + (size_t)hbase * 64;   // SGPR-uniform base
    const float* bp  = base + hbase;
    float* kp = K + ((size_t)b * H_ + hbase) * L_ + l;

    #pragma unroll 2
    for (int h = 0; h < 128; ++h) {
        float acc = bp[h];
        const float* cr = cbp + h * 64;           // uniform -> s_load
        #pragma unroll
        for (int n = 0; n < 64; ++n) acc = fmaf(cr[n], sv[n], acc);
        kp[(size_t)h * L_] = acc;
    }
}

// ---------------------------------------------------------------------------
extern "C" void kernel_launch(void* const* d_in, const int* in_sizes, int n_in,
                              void* d_out, int out_size, void* d_ws, size_t ws_size,
                              hipStream_t stream) {
    const float* du   = (const float*)d_in[0];  // [B][H][L]
    const float* C    = (const float*)d_in[1];  // [H][N]
    const float* Bvec = (const float*)d_in[2];  // [N]
    const float* A    = (const float*)d_in[3];  // [N][N]
    const float* W    = (const float*)d_in[4];  // [N][H]
    float* K = (float*)d_out;                   // [B][H][L]

    float* ws   = (float*)d_ws;
    float* S    = ws;                                  // B*N*L = 2,097,152 f
    float* Wt   = ws + (size_t)B_ * N_ * L_;           // H*N
    float* CB   = Wt + (size_t)H_ * N_;                // H*N
    float* base = CB + (size_t)H_ * N_;                // H

    setup_kernel<<<16, 256, 0, stream>>>(C, Bvec, A, W, Wt, CB, base);
    dA_kernel<<<dim3(L_ / 64, B_), 512, 0, stream>>>(du, Wt, S);
    scan_kernel<<<dim3(N_, B_), 256, 0, stream>>>(S);
    out_kernel<<<dim3(L_ / 64, B_), 512, 0, stream>>>(S, CB, base, K);
}

// Round 5
// 294.940 us; speedup vs baseline: 2.4838x; 1.7680x over previous
//
#include <hip/hip_runtime.h>
#include <hip/hip_bf16.h>

#define B_ 8
#define H_ 1024
#define N_ 64
#define L_ 4096

typedef float f32x4 __attribute__((ext_vector_type(4)));
typedef int   i32x4 __attribute__((ext_vector_type(4)));

__device__ __forceinline__ unsigned bfpk(float a, float b) {
    unsigned ua = (unsigned)__builtin_bit_cast(unsigned short, __float2bfloat16(a));
    unsigned ub = (unsigned)__builtin_bit_cast(unsigned short, __float2bfloat16(b));
    return ua | (ub << 16);
}

// D = A(16x32,bf16) * B(32x16,bf16) + D(f32). s_nop 1 guards VALU->MFMA read.
// Hazard MFMA->VALU/VMEM is handled by ACC fences below (data-dependent nops).
__device__ __forceinline__ void mfma16(f32x4& d, i32x4 a, i32x4 b) {
    asm volatile("s_nop 1\n\tv_mfma_f32_16x16x32_bf16 %0, %1, %2, %0"
                 : "+v"(d) : "v"(a), "v"(b));
}

// ---------------------------------------------------------------------------
// setup: Wswz  = W as dA-GEMM B-frags  (frag (kt,nt): lane(lq,lm) -> n=nt*16+lm,
//                elem j -> h=kt*32+lq*8+j), bf16, frag-contiguous
//        CBswz = (C*Bvec) as out-GEMM A-frags (frag (kt,mt): lane -> h=mt*16+lm,
//                elem j -> n=kt*32+lq*8+j), bf16
//        base[h] = C @ (A @ Bvec)  (f32)
// ---------------------------------------------------------------------------
__global__ __launch_bounds__(256) void setup_kernel(
    const float* __restrict__ C, const float* __restrict__ Bvec,
    const float* __restrict__ A, const float* __restrict__ W,
    unsigned short* __restrict__ Wswz, unsigned short* __restrict__ CBswz,
    float* __restrict__ base)
{
    const int tid = threadIdx.x, bid = blockIdx.x;
    const int lane = tid & 63, lm = lane & 15, lq = lane >> 4;
    if (bid < 32) {
        const int kt = bid, nt = tid >> 6;
        const float* src = W + (size_t)(nt * 16 + lm) * H_ + kt * 32 + lq * 8;
        float4 a = *(const float4*)src, c = *(const float4*)(src + 4);
        i32x4 o;
        o.x = bfpk(a.x, a.y); o.y = bfpk(a.z, a.w);
        o.z = bfpk(c.x, c.y); o.w = bfpk(c.z, c.w);
        ((i32x4*)Wswz)[(kt * 4 + nt) * 64 + lane] = o;
    } else if (bid < 64) {
        const int u = (bid - 32) * 4 + (tid >> 6);   // u = kt*64 + mt
        const int mt = u & 63, kt = u >> 6;
        const int h = mt * 16 + lm, n0 = kt * 32 + lq * 8;
        const float* src = C + (size_t)h * 64 + n0;
        float4 a = *(const float4*)src, c = *(const float4*)(src + 4);
        float4 v1 = *(const float4*)(Bvec + n0), v2 = *(const float4*)(Bvec + n0 + 4);
        i32x4 o;
        o.x = bfpk(a.x * v1.x, a.y * v1.y); o.y = bfpk(a.z * v1.z, a.w * v1.w);
        o.z = bfpk(c.x * v2.x, c.y * v2.y); o.w = bfpk(c.z * v2.z, c.w * v2.w);
        ((i32x4*)CBswz)[u * 64 + lane] = o;
    } else {
        __shared__ float abv[64];
        __shared__ float bv[64];
        if (tid < 64) bv[tid] = Bvec[tid];
        __syncthreads();
        if (tid < 64) {
            float s = 0.f;
            const float* ar = A + tid * 64;
            #pragma unroll 8
            for (int m = 0; m < 64; ++m) s += ar[m] * bv[m];
            abv[tid] = s;
        }
        __syncthreads();
        #pragma unroll
        for (int r = 0; r < 4; ++r) {
            int h = tid + r * 256;
            float s = 0.f;
            const float* cr = C + (size_t)h * 64;
            #pragma unroll 8
            for (int n = 0; n < 64; ++n) s += cr[n] * abv[n];
            base[h] = s;
        }
    }
}

// ---------------------------------------------------------------------------
// dA-GEMM: dA[b][l][n] = sum_h du[b][h][l] * W[n][h]   (A=du m=l, B=Wswz)
// block = 4 waves x 16-l subtiles (64 l total), all 64 n, K=1024 in 32 steps.
// dA stored f32 [B][L][N] (8 MB, L2-resident). Also emits per-subtile column
// sums Tsum[b][stile][n] (f32) from the f32 accumulators.
// ---------------------------------------------------------------------------
__global__ __launch_bounds__(256) void dA_kernel(
    const float* __restrict__ du, const unsigned short* __restrict__ Wswz,
    float* __restrict__ dAf, float* __restrict__ Tsum)
{
    const int tid = threadIdx.x, lane = tid & 63, w = tid >> 6;
    const int lt = blockIdx.x, b = blockIdx.y;
    const int lm = lane & 15, lq = lane >> 4;
    const int myl = lt * 64 + w * 16 + lm;
    const float* dup = du + (size_t)b * H_ * L_ + myl;

    f32x4 acc[4] = {f32x4{0,0,0,0}, f32x4{0,0,0,0}, f32x4{0,0,0,0}, f32x4{0,0,0,0}};
    #pragma unroll 4
    for (int kt = 0; kt < 32; ++kt) {
        const int h0 = kt * 32 + lq * 8;
        float d[8];
        #pragma unroll
        for (int j = 0; j < 8; ++j) d[j] = dup[(size_t)(h0 + j) * L_];
        i32x4 af;
        af.x = bfpk(d[0], d[1]); af.y = bfpk(d[2], d[3]);
        af.z = bfpk(d[4], d[5]); af.w = bfpk(d[6], d[7]);
        #pragma unroll
        for (int nt = 0; nt < 4; ++nt) {
            i32x4 bfr = ((const i32x4*)Wswz)[(kt * 4 + nt) * 64 + lane];
            mfma16(acc[nt], af, bfr);
        }
    }
    // Data-dependent hazard fence: ties all accs so consumers MUST follow the
    // nops; covers MFMA-write -> VALU/VMEM-read wait states.
    asm volatile("s_nop 7\n\ts_nop 7"
                 : "+v"(acc[0]), "+v"(acc[1]), "+v"(acc[2]), "+v"(acc[3]));

    // store dA f32: lane: col n = nt*16+lm, rows l = subtile + lq*4 + r
    float* outp = dAf + ((size_t)b * L_ + (size_t)lt * 64 + w * 16 + lq * 4) * 64 + lm;
    #pragma unroll
    for (int nt = 0; nt < 4; ++nt) {
        #pragma unroll
        for (int r = 0; r < 4; ++r)
            outp[(size_t)r * 64 + nt * 16] = acc[nt][r];
    }
    // per-subtile (16 l) column sums -> Tsum
    float s[4];
    #pragma unroll
    for (int nt = 0; nt < 4; ++nt) {
        float v = acc[nt][0] + acc[nt][1] + acc[nt][2] + acc[nt][3];
        v += __shfl_xor(v, 16);
        v += __shfl_xor(v, 32);
        s[nt] = v;
    }
    float outv = (lq == 0) ? s[0] : (lq == 1) ? s[1] : (lq == 2) ? s[2] : s[3];
    Tsum[((size_t)b * 256 + lt * 4 + w) * 64 + lq * 16 + lm] = outv;
}

// ---------------------------------------------------------------------------
// Exclusive scan of Tsum over the 256 subtiles, one wave per (b,n) row.
// grid: 64 blocks x 512 thr; wave wid=(blockIdx*8+w) -> b=wid>>6, n=wid&63.
// ---------------------------------------------------------------------------
__global__ __launch_bounds__(512) void pscan_kernel(float* __restrict__ Tsum)
{
    const int tid = threadIdx.x, lane = tid & 63, w = tid >> 6;
    const int wid = blockIdx.x * 8 + w;
    const int b = wid >> 6, n = wid & 63;
    float* p = Tsum + (size_t)b * 256 * 64 + n;

    float v[4];
    #pragma unroll
    for (int j = 0; j < 4; ++j) v[j] = p[(size_t)(lane * 4 + j) * 64];
    float sum = v[0] + v[1] + v[2] + v[3];

    float sc = sum;
    #pragma unroll
    for (int d = 1; d < 64; d <<= 1) {
        float u = __shfl_up(sc, d);
        if (lane >= d) sc += u;
    }
    float run = sc - sum;  // exclusive prefix of this lane's 4-group
    #pragma unroll
    for (int j = 0; j < 4; ++j) {
        float t = v[j];
        p[(size_t)(lane * 4 + j) * 64] = run;
        run += t;
    }
}

// ---------------------------------------------------------------------------
// out-GEMM: K[b][h][l] = base[h] + sum_n CB[h][n] * S[n][l]
// block = one 16-l subtile x all 1024 h (4 waves x 256 h), K=64 in 2 steps.
// S built in-block: f32 local cumsum of dA + Ppre offset, staged in padded
// f32 LDS [16][65]; B-frags packed to bf16 via plain ds reads.
// ---------------------------------------------------------------------------
__global__ __launch_bounds__(256) void out_kernel(
    const float* __restrict__ dAf, const float* __restrict__ Ppre,
    const unsigned short* __restrict__ CBswz, const float* __restrict__ base,
    float* __restrict__ K)
{
    __shared__ float slds[16][65];
    __shared__ float tot[4][64];
    const int tid = threadIdx.x;
    const int stile = blockIdx.x, b = blockIdx.y;
    const int l0 = stile * 16;
    {
        const int n = tid & 63, q = tid >> 6;
        const float* dp = dAf + ((size_t)b * L_ + l0 + q * 4) * 64 + n;
        float v0 = dp[0], v1 = dp[64], v2 = dp[128], v3 = dp[192];
        float s1 = v0 + v1, s2 = s1 + v2, s3 = s2 + v3;
        tot[q][n] = s3;
        __syncthreads();
        float off = Ppre[((size_t)b * 256 + stile) * 64 + n];
        if (q > 0) off += tot[0][n];
        if (q > 1) off += tot[1][n];
        if (q > 2) off += tot[2][n];
        slds[q * 4 + 0][n] = off + v0;
        slds[q * 4 + 1][n] = off + s1;
        slds[q * 4 + 2][n] = off + s2;
        slds[q * 4 + 3][n] = off + s3;
    }
    __syncthreads();

    const int lane = tid & 63, w = tid >> 6;
    const int lm = lane & 15, lq = lane >> 4;
    // B-frag: lane(lq,lm): col(l)=lm, elem j -> n = kt*32 + lq*8 + j
    i32x4 sf[2];
    #pragma unroll
    for (int kt = 0; kt < 2; ++kt) {
        const float* sr = &slds[lm][kt * 32 + lq * 8];
        float x0 = sr[0], x1 = sr[1], x2 = sr[2], x3 = sr[3];
        float x4 = sr[4], x5 = sr[5], x6 = sr[6], x7 = sr[7];
        i32x4 t;
        t.x = bfpk(x0, x1); t.y = bfpk(x2, x3);
        t.z = bfpk(x4, x5); t.w = bfpk(x6, x7);
        sf[kt] = t;
    }

    f32x4 acc[16];
    #pragma unroll
    for (int i = 0; i < 16; ++i) {
        float4 bb = *(const float4*)(base + w * 256 + i * 16 + lq * 4);
        acc[i] = f32x4{bb.x, bb.y, bb.z, bb.w};
    }
    #pragma unroll
    for (int kt = 0; kt < 2; ++kt) {
        #pragma unroll
        for (int i = 0; i < 16; ++i) {
            i32x4 cb = ((const i32x4*)CBswz)[(kt * 64 + w * 16 + i) * 64 + lane];
            mfma16(acc[i], cb, sf[kt]);
        }
    }
    asm volatile("s_nop 7\n\ts_nop 7"
                 : "+v"(acc[0]), "+v"(acc[1]), "+v"(acc[2]), "+v"(acc[3]),
                   "+v"(acc[4]), "+v"(acc[5]), "+v"(acc[6]), "+v"(acc[7]),
                   "+v"(acc[8]), "+v"(acc[9]), "+v"(acc[10]), "+v"(acc[11]),
                   "+v"(acc[12]), "+v"(acc[13]), "+v"(acc[14]), "+v"(acc[15]));

    float* kp = K + ((size_t)b * H_ + w * 256 + lq * 4) * (size_t)L_ + l0 + lm;
    #pragma unroll
    for (int i = 0; i < 16; ++i) {
        #pragma unroll
        for (int r = 0; r < 4; ++r)
            kp[((size_t)i * 16 + r) * L_] = acc[i][r];
    }
}

// ---------------------------------------------------------------------------
extern "C" void kernel_launch(void* const* d_in, const int* in_sizes, int n_in,
                              void* d_out, int out_size, void* d_ws, size_t ws_size,
                              hipStream_t stream) {
    const float* du   = (const float*)d_in[0];  // [B][H][L]
    const float* C    = (const float*)d_in[1];  // [H][N]
    const float* Bvec = (const float*)d_in[2];  // [N]
    const float* A    = (const float*)d_in[3];  // [N][N]
    const float* W    = (const float*)d_in[4];  // [N][H]
    float* K = (float*)d_out;                   // [B][H][L]

    float* dAf = (float*)d_ws;                                     // B*L*64 f32 = 8 MB
    unsigned short* Wswz  = (unsigned short*)(dAf + (size_t)B_ * L_ * 64);  // 65536 u16
    unsigned short* CBswz = Wswz + 65536;                          // 65536 u16
    float* Tsum = (float*)(CBswz + 65536);                         // 8*256*64 f32
    float* base = Tsum + (size_t)B_ * 256 * 64;                    // 1024 f32

    setup_kernel<<<65, 256, 0, stream>>>(C, Bvec, A, W, Wswz, CBswz, base);
    dA_kernel<<<dim3(64, B_), 256, 0, stream>>>(du, Wswz, dAf, Tsum);
    pscan_kernel<<<64, 512, 0, stream>>>(Tsum);
    out_kernel<<<dim3(256, B_), 256, 0, stream>>>(dAf, Tsum, CBswz, base, K);
}

// Round 6
// 292.490 us; speedup vs baseline: 2.5046x; 1.0084x over previous
//
#include <hip/hip_runtime.h>
#include <hip/hip_bf16.h>

#define B_ 8
#define H_ 1024
#define N_ 64
#define L_ 4096

typedef float f32x4 __attribute__((ext_vector_type(4)));
typedef int   i32x4 __attribute__((ext_vector_type(4)));

__device__ __forceinline__ unsigned bfpk(float a, float b) {
    unsigned ua = (unsigned)__builtin_bit_cast(unsigned short, __float2bfloat16(a));
    unsigned ub = (unsigned)__builtin_bit_cast(unsigned short, __float2bfloat16(b));
    return ua | (ub << 16);
}

// D = A(16x32,bf16) * B(32x16,bf16) + D(f32). s_nop 1 guards VALU->MFMA read.
// MFMA->VALU/VMEM hazard is handled by data-dependent ACC fences below.
__device__ __forceinline__ void mfma16(f32x4& d, i32x4 a, i32x4 b) {
    asm volatile("s_nop 1\n\tv_mfma_f32_16x16x32_bf16 %0, %1, %2, %0"
                 : "+v"(d) : "v"(a), "v"(b));
}

// ---------------------------------------------------------------------------
// setup: Wswz  = W as dA-GEMM B-frags  (frag (kt,nt): lane(lq,lm) -> n=nt*16+lm,
//                elem j -> h=kt*32+lq*8+j), bf16, frag-contiguous
//        CBswz = (C*Bvec) as out-GEMM A-frags (frag (kt,mt): lane -> h=mt*16+lm,
//                elem j -> n=kt*32+lq*8+j), bf16
//        base[h] = C @ (A @ Bvec)  (f32)
// ---------------------------------------------------------------------------
__global__ __launch_bounds__(256) void setup_kernel(
    const float* __restrict__ C, const float* __restrict__ Bvec,
    const float* __restrict__ A, const float* __restrict__ W,
    unsigned short* __restrict__ Wswz, unsigned short* __restrict__ CBswz,
    float* __restrict__ base)
{
    const int tid = threadIdx.x, bid = blockIdx.x;
    const int lane = tid & 63, lm = lane & 15, lq = lane >> 4;
    if (bid < 32) {
        const int kt = bid, nt = tid >> 6;
        const float* src = W + (size_t)(nt * 16 + lm) * H_ + kt * 32 + lq * 8;
        float4 a = *(const float4*)src, c = *(const float4*)(src + 4);
        i32x4 o;
        o.x = bfpk(a.x, a.y); o.y = bfpk(a.z, a.w);
        o.z = bfpk(c.x, c.y); o.w = bfpk(c.z, c.w);
        ((i32x4*)Wswz)[(kt * 4 + nt) * 64 + lane] = o;
    } else if (bid < 64) {
        const int u = (bid - 32) * 4 + (tid >> 6);   // u = kt*64 + mt
        const int mt = u & 63, kt = u >> 6;
        const int h = mt * 16 + lm, n0 = kt * 32 + lq * 8;
        const float* src = C + (size_t)h * 64 + n0;
        float4 a = *(const float4*)src, c = *(const float4*)(src + 4);
        float4 v1 = *(const float4*)(Bvec + n0), v2 = *(const float4*)(Bvec + n0 + 4);
        i32x4 o;
        o.x = bfpk(a.x * v1.x, a.y * v1.y); o.y = bfpk(a.z * v1.z, a.w * v1.w);
        o.z = bfpk(c.x * v2.x, c.y * v2.y); o.w = bfpk(c.z * v2.z, c.w * v2.w);
        ((i32x4*)CBswz)[u * 64 + lane] = o;
    } else {
        __shared__ float abv[64];
        __shared__ float bv[64];
        if (tid < 64) bv[tid] = Bvec[tid];
        __syncthreads();
        if (tid < 64) {
            float s = 0.f;
            const float* ar = A + tid * 64;
            #pragma unroll 8
            for (int m = 0; m < 64; ++m) s += ar[m] * bv[m];
            abv[tid] = s;
        }
        __syncthreads();
        #pragma unroll
        for (int r = 0; r < 4; ++r) {
            int h = tid + r * 256;
            float s = 0.f;
            const float* cr = C + (size_t)h * 64;
            #pragma unroll 8
            for (int n = 0; n < 64; ++n) s += cr[n] * abv[n];
            base[h] = s;
        }
    }
}

// ---------------------------------------------------------------------------
// dA-GEMM: dA[b][l][n] = sum_h du[b][h][l] * W[n][h]   (A=du m=l, B=Wswz)
// K-SPLIT x2: block = 8 waves; wave (st=w&3, half=w>>2) computes l-subtile st
// (16 l) over h in [half*512, half*512+512). half==1 partials go through LDS
// (16 KB); half==0 waves combine, store dA f32 [B][L][N] + emit per-subtile
// column sums Tsum. 16 waves/CU (vs 8) for latency hiding on du loads.
// ---------------------------------------------------------------------------
__global__ __launch_bounds__(512) void dA_kernel(
    const float* __restrict__ du, const unsigned short* __restrict__ Wswz,
    float* __restrict__ dAf, float* __restrict__ Tsum)
{
    __shared__ float red[4][64][16];  // [subtile][lane][acc-reg] = 16 KB
    const int tid = threadIdx.x, lane = tid & 63, w = tid >> 6;
    const int st = w & 3, half = w >> 2;
    const int lt = blockIdx.x, b = blockIdx.y;
    const int lm = lane & 15, lq = lane >> 4;
    const int myl = lt * 64 + st * 16 + lm;
    const float* dup = du + ((size_t)b * H_ + (size_t)half * 512) * L_ + myl;

    f32x4 acc[4] = {f32x4{0,0,0,0}, f32x4{0,0,0,0}, f32x4{0,0,0,0}, f32x4{0,0,0,0}};
    #pragma unroll 4
    for (int kt = 0; kt < 16; ++kt) {
        const int h0 = kt * 32 + lq * 8;
        float d[8];
        #pragma unroll
        for (int j = 0; j < 8; ++j) d[j] = dup[(size_t)(h0 + j) * L_];
        i32x4 af;
        af.x = bfpk(d[0], d[1]); af.y = bfpk(d[2], d[3]);
        af.z = bfpk(d[4], d[5]); af.w = bfpk(d[6], d[7]);
        const int ktg = half * 16 + kt;
        #pragma unroll
        for (int nt = 0; nt < 4; ++nt) {
            i32x4 bfr = ((const i32x4*)Wswz)[(ktg * 4 + nt) * 64 + lane];
            mfma16(acc[nt], af, bfr);
        }
    }
    // Data-dependent hazard fence: consumers of acc must follow these nops.
    asm volatile("s_nop 7\n\ts_nop 7"
                 : "+v"(acc[0]), "+v"(acc[1]), "+v"(acc[2]), "+v"(acc[3]));

    if (half == 1) {
        #pragma unroll
        for (int nt = 0; nt < 4; ++nt)
            #pragma unroll
            for (int r = 0; r < 4; ++r)
                red[st][lane][nt * 4 + r] = acc[nt][r];
    }
    __syncthreads();
    if (half == 1) return;

    #pragma unroll
    for (int nt = 0; nt < 4; ++nt)
        #pragma unroll
        for (int r = 0; r < 4; ++r)
            acc[nt][r] += red[st][lane][nt * 4 + r];

    // store dA f32: lane: col n = nt*16+lm, rows l = subtile + lq*4 + r
    float* outp = dAf + ((size_t)b * L_ + (size_t)lt * 64 + st * 16 + lq * 4) * 64 + lm;
    #pragma unroll
    for (int nt = 0; nt < 4; ++nt) {
        #pragma unroll
        for (int r = 0; r < 4; ++r)
            outp[(size_t)r * 64 + nt * 16] = acc[nt][r];
    }
    // per-subtile (16 l) column sums -> Tsum
    float s[4];
    #pragma unroll
    for (int nt = 0; nt < 4; ++nt) {
        float v = acc[nt][0] + acc[nt][1] + acc[nt][2] + acc[nt][3];
        v += __shfl_xor(v, 16);
        v += __shfl_xor(v, 32);
        s[nt] = v;
    }
    float outv = (lq == 0) ? s[0] : (lq == 1) ? s[1] : (lq == 2) ? s[2] : s[3];
    Tsum[((size_t)b * 256 + lt * 4 + st) * 64 + lq * 16 + lm] = outv;
}

// ---------------------------------------------------------------------------
// Exclusive scan of Tsum over the 256 subtiles, one wave per (b,n) row.
// ---------------------------------------------------------------------------
__global__ __launch_bounds__(512) void pscan_kernel(float* __restrict__ Tsum)
{
    const int tid = threadIdx.x, lane = tid & 63, w = tid >> 6;
    const int wid = blockIdx.x * 8 + w;
    const int b = wid >> 6, n = wid & 63;
    float* p = Tsum + (size_t)b * 256 * 64 + n;

    float v[4];
    #pragma unroll
    for (int j = 0; j < 4; ++j) v[j] = p[(size_t)(lane * 4 + j) * 64];
    float sum = v[0] + v[1] + v[2] + v[3];

    float sc = sum;
    #pragma unroll
    for (int d = 1; d < 64; d <<= 1) {
        float u = __shfl_up(sc, d);
        if (lane >= d) sc += u;
    }
    float run = sc - sum;  // exclusive prefix of this lane's 4-group
    #pragma unroll
    for (int j = 0; j < 4; ++j) {
        float t = v[j];
        p[(size_t)(lane * 4 + j) * 64] = run;
        run += t;
    }
}

// ---------------------------------------------------------------------------
// out-GEMM: K[b][h][l] = base[h] + sum_n CB[h][n] * S[n][l]
// block = one 16-l subtile x all 1024 h (4 waves x 256 h), K=64 in 2 steps.
// S built in-block: f32 local cumsum of dA + Ppre offset, staged in padded
// f32 LDS [16][65]; B-frags packed to bf16 via plain ds reads.
// ---------------------------------------------------------------------------
__global__ __launch_bounds__(256) void out_kernel(
    const float* __restrict__ dAf, const float* __restrict__ Ppre,
    const unsigned short* __restrict__ CBswz, const float* __restrict__ base,
    float* __restrict__ K)
{
    __shared__ float slds[16][65];
    __shared__ float tot[4][64];
    const int tid = threadIdx.x;
    const int stile = blockIdx.x, b = blockIdx.y;
    const int l0 = stile * 16;
    {
        const int n = tid & 63, q = tid >> 6;
        const float* dp = dAf + ((size_t)b * L_ + l0 + q * 4) * 64 + n;
        float v0 = dp[0], v1 = dp[64], v2 = dp[128], v3 = dp[192];
        float s1 = v0 + v1, s2 = s1 + v2, s3 = s2 + v3;
        tot[q][n] = s3;
        __syncthreads();
        float off = Ppre[((size_t)b * 256 + stile) * 64 + n];
        if (q > 0) off += tot[0][n];
        if (q > 1) off += tot[1][n];
        if (q > 2) off += tot[2][n];
        slds[q * 4 + 0][n] = off + v0;
        slds[q * 4 + 1][n] = off + s1;
        slds[q * 4 + 2][n] = off + s2;
        slds[q * 4 + 3][n] = off + s3;
    }
    __syncthreads();

    const int lane = tid & 63, w = tid >> 6;
    const int lm = lane & 15, lq = lane >> 4;
    // B-frag: lane(lq,lm): col(l)=lm, elem j -> n = kt*32 + lq*8 + j
    i32x4 sf[2];
    #pragma unroll
    for (int kt = 0; kt < 2; ++kt) {
        const float* sr = &slds[lm][kt * 32 + lq * 8];
        float x0 = sr[0], x1 = sr[1], x2 = sr[2], x3 = sr[3];
        float x4 = sr[4], x5 = sr[5], x6 = sr[6], x7 = sr[7];
        i32x4 t;
        t.x = bfpk(x0, x1); t.y = bfpk(x2, x3);
        t.z = bfpk(x4, x5); t.w = bfpk(x6, x7);
        sf[kt] = t;
    }

    f32x4 acc[16];
    #pragma unroll
    for (int i = 0; i < 16; ++i) {
        float4 bb = *(const float4*)(base + w * 256 + i * 16 + lq * 4);
        acc[i] = f32x4{bb.x, bb.y, bb.z, bb.w};
    }
    #pragma unroll
    for (int kt = 0; kt < 2; ++kt) {
        #pragma unroll
        for (int i = 0; i < 16; ++i) {
            i32x4 cb = ((const i32x4*)CBswz)[(kt * 64 + w * 16 + i) * 64 + lane];
            mfma16(acc[i], cb, sf[kt]);
        }
    }
    asm volatile("s_nop 7\n\ts_nop 7"
                 : "+v"(acc[0]), "+v"(acc[1]), "+v"(acc[2]), "+v"(acc[3]),
                   "+v"(acc[4]), "+v"(acc[5]), "+v"(acc[6]), "+v"(acc[7]),
                   "+v"(acc[8]), "+v"(acc[9]), "+v"(acc[10]), "+v"(acc[11]),
                   "+v"(acc[12]), "+v"(acc[13]), "+v"(acc[14]), "+v"(acc[15]));

    float* kp = K + ((size_t)b * H_ + w * 256 + lq * 4) * (size_t)L_ + l0 + lm;
    #pragma unroll
    for (int i = 0; i < 16; ++i) {
        #pragma unroll
        for (int r = 0; r < 4; ++r)
            kp[((size_t)i * 16 + r) * L_] = acc[i][r];
    }
}

// ---------------------------------------------------------------------------
extern "C" void kernel_launch(void* const* d_in, const int* in_sizes, int n_in,
                              void* d_out, int out_size, void* d_ws, size_t ws_size,
                              hipStream_t stream) {
    const float* du   = (const float*)d_in[0];  // [B][H][L]
    const float* C    = (const float*)d_in[1];  // [H][N]
    const float* Bvec = (const float*)d_in[2];  // [N]
    const float* A    = (const float*)d_in[3];  // [N][N]
    const float* W    = (const float*)d_in[4];  // [N][H]
    float* K = (float*)d_out;                   // [B][H][L]

    float* dAf = (float*)d_ws;                                     // B*L*64 f32 = 8 MB
    unsigned short* Wswz  = (unsigned short*)(dAf + (size_t)B_ * L_ * 64);  // 65536 u16
    unsigned short* CBswz = Wswz + 65536;                          // 65536 u16
    float* Tsum = (float*)(CBswz + 65536);                         // 8*256*64 f32
    float* base = Tsum + (size_t)B_ * 256 * 64;                    // 1024 f32

    setup_kernel<<<65, 256, 0, stream>>>(C, Bvec, A, W, Wswz, CBswz, base);
    dA_kernel<<<dim3(64, B_), 512, 0, stream>>>(du, Wswz, dAf, Tsum);
    pscan_kernel<<<64, 512, 0, stream>>>(Tsum);
    out_kernel<<<dim3(256, B_), 256, 0, stream>>>(dAf, Tsum, CBswz, base, K);
}

// Round 7
// 276.454 us; speedup vs baseline: 2.6499x; 1.0580x over previous
//
#include <hip/hip_runtime.h>
#include <hip/hip_bf16.h>

#define B_ 8
#define H_ 1024
#define N_ 64
#define L_ 4096

typedef float f32x4 __attribute__((ext_vector_type(4)));
typedef int   i32x4 __attribute__((ext_vector_type(4)));

__device__ __forceinline__ unsigned bfpk(float a, float b) {
    unsigned ua = (unsigned)__builtin_bit_cast(unsigned short, __float2bfloat16(a));
    unsigned ub = (unsigned)__builtin_bit_cast(unsigned short, __float2bfloat16(b));
    return ua | (ub << 16);
}

// D = A(16x32,bf16) * B(32x16,bf16) + D(f32). s_nop 1 guards VALU->MFMA read.
// MFMA->VALU/VMEM hazard is handled by data-dependent ACC fences below.
__device__ __forceinline__ void mfma16(f32x4& d, i32x4 a, i32x4 b) {
    asm volatile("s_nop 1\n\tv_mfma_f32_16x16x32_bf16 %0, %1, %2, %0"
                 : "+v"(d) : "v"(a), "v"(b));
}

// ---------------------------------------------------------------------------
// setup: Wswz  = W as dA-GEMM B-frags  (frag (kt,nt): lane(lq,lm) -> n=nt*16+lm,
//                elem j -> h=kt*32+lq*8+j), bf16, frag-contiguous
//        CBswz = (C*Bvec) as out-GEMM A-frags (frag (kt,mt): lane -> h=mt*16+lm,
//                elem j -> n=kt*32+lq*8+j), bf16
//        base[h] = C @ (A @ Bvec)  (f32), 4 blocks x 256 h
// ---------------------------------------------------------------------------
__global__ __launch_bounds__(256) void setup_kernel(
    const float* __restrict__ C, const float* __restrict__ Bvec,
    const float* __restrict__ A, const float* __restrict__ W,
    unsigned short* __restrict__ Wswz, unsigned short* __restrict__ CBswz,
    float* __restrict__ base)
{
    const int tid = threadIdx.x, bid = blockIdx.x;
    const int lane = tid & 63, lm = lane & 15, lq = lane >> 4;
    if (bid < 32) {
        const int kt = bid, nt = tid >> 6;
        const float* src = W + (size_t)(nt * 16 + lm) * H_ + kt * 32 + lq * 8;
        float4 a = *(const float4*)src, c = *(const float4*)(src + 4);
        i32x4 o;
        o.x = bfpk(a.x, a.y); o.y = bfpk(a.z, a.w);
        o.z = bfpk(c.x, c.y); o.w = bfpk(c.z, c.w);
        ((i32x4*)Wswz)[(kt * 4 + nt) * 64 + lane] = o;
    } else if (bid < 64) {
        const int u = (bid - 32) * 4 + (tid >> 6);   // u = kt*64 + mt
        const int mt = u & 63, kt = u >> 6;
        const int h = mt * 16 + lm, n0 = kt * 32 + lq * 8;
        const float* src = C + (size_t)h * 64 + n0;
        float4 a = *(const float4*)src, c = *(const float4*)(src + 4);
        float4 v1 = *(const float4*)(Bvec + n0), v2 = *(const float4*)(Bvec + n0 + 4);
        i32x4 o;
        o.x = bfpk(a.x * v1.x, a.y * v1.y); o.y = bfpk(a.z * v1.z, a.w * v1.w);
        o.z = bfpk(c.x * v2.x, c.y * v2.y); o.w = bfpk(c.z * v2.z, c.w * v2.w);
        ((i32x4*)CBswz)[u * 64 + lane] = o;
    } else {
        __shared__ float abv[64];
        __shared__ float bv[64];
        if (tid < 64) bv[tid] = Bvec[tid];
        __syncthreads();
        if (tid < 64) {
            float s = 0.f;
            const float* ar = A + tid * 64;
            #pragma unroll 8
            for (int m = 0; m < 64; ++m) s += ar[m] * bv[m];
            abv[tid] = s;
        }
        __syncthreads();
        const int h = (bid - 64) * 256 + tid;
        float s = 0.f;
        const float* cr = C + (size_t)h * 64;
        #pragma unroll 8
        for (int n = 0; n < 64; ++n) s += cr[n] * abv[n];
        base[h] = s;
    }
}

// ---------------------------------------------------------------------------
// dA-GEMM: dA[b][l][n] = sum_h du[b][h][l] * W[n][h]   (A=du m=l, B=Wswz)
// K-SPLIT x2: block = 8 waves; wave (st=w&3, half=w>>2) computes l-subtile st
// over h in [half*512, half*512+512). LDS-combine; emit dA f32 + Tsum.
// ---------------------------------------------------------------------------
__global__ __launch_bounds__(512) void dA_kernel(
    const float* __restrict__ du, const unsigned short* __restrict__ Wswz,
    float* __restrict__ dAf, float* __restrict__ Tsum)
{
    __shared__ float red[4][64][16];  // 16 KB
    const int tid = threadIdx.x, lane = tid & 63, w = tid >> 6;
    const int st = w & 3, half = w >> 2;
    const int lt = blockIdx.x, b = blockIdx.y;
    const int lm = lane & 15, lq = lane >> 4;
    const int myl = lt * 64 + st * 16 + lm;
    const float* dup = du + ((size_t)b * H_ + (size_t)half * 512) * L_ + myl;

    f32x4 acc[4] = {f32x4{0,0,0,0}, f32x4{0,0,0,0}, f32x4{0,0,0,0}, f32x4{0,0,0,0}};
    #pragma unroll 4
    for (int kt = 0; kt < 16; ++kt) {
        const int h0 = kt * 32 + lq * 8;
        float d[8];
        #pragma unroll
        for (int j = 0; j < 8; ++j) d[j] = dup[(size_t)(h0 + j) * L_];
        i32x4 af;
        af.x = bfpk(d[0], d[1]); af.y = bfpk(d[2], d[3]);
        af.z = bfpk(d[4], d[5]); af.w = bfpk(d[6], d[7]);
        const int ktg = half * 16 + kt;
        #pragma unroll
        for (int nt = 0; nt < 4; ++nt) {
            i32x4 bfr = ((const i32x4*)Wswz)[(ktg * 4 + nt) * 64 + lane];
            mfma16(acc[nt], af, bfr);
        }
    }
    asm volatile("s_nop 7\n\ts_nop 7"
                 : "+v"(acc[0]), "+v"(acc[1]), "+v"(acc[2]), "+v"(acc[3]));

    if (half == 1) {
        #pragma unroll
        for (int nt = 0; nt < 4; ++nt)
            #pragma unroll
            for (int r = 0; r < 4; ++r)
                red[st][lane][nt * 4 + r] = acc[nt][r];
    }
    __syncthreads();
    if (half == 1) return;

    #pragma unroll
    for (int nt = 0; nt < 4; ++nt)
        #pragma unroll
        for (int r = 0; r < 4; ++r)
            acc[nt][r] += red[st][lane][nt * 4 + r];

    float* outp = dAf + ((size_t)b * L_ + (size_t)lt * 64 + st * 16 + lq * 4) * 64 + lm;
    #pragma unroll
    for (int nt = 0; nt < 4; ++nt) {
        #pragma unroll
        for (int r = 0; r < 4; ++r)
            outp[(size_t)r * 64 + nt * 16] = acc[nt][r];
    }
    float s[4];
    #pragma unroll
    for (int nt = 0; nt < 4; ++nt) {
        float v = acc[nt][0] + acc[nt][1] + acc[nt][2] + acc[nt][3];
        v += __shfl_xor(v, 16);
        v += __shfl_xor(v, 32);
        s[nt] = v;
    }
    float outv = (lq == 0) ? s[0] : (lq == 1) ? s[1] : (lq == 2) ? s[2] : s[3];
    Tsum[((size_t)b * 256 + lt * 4 + st) * 64 + lq * 16 + lm] = outv;
}

// ---------------------------------------------------------------------------
// Exclusive scan of Tsum over the 256 subtiles, one wave per (b,n) row.
// ---------------------------------------------------------------------------
__global__ __launch_bounds__(512) void pscan_kernel(float* __restrict__ Tsum)
{
    const int tid = threadIdx.x, lane = tid & 63, w = tid >> 6;
    const int wid = blockIdx.x * 8 + w;
    const int b = wid >> 6, n = wid & 63;
    float* p = Tsum + (size_t)b * 256 * 64 + n;

    float v[4];
    #pragma unroll
    for (int j = 0; j < 4; ++j) v[j] = p[(size_t)(lane * 4 + j) * 64];
    float sum = v[0] + v[1] + v[2] + v[3];

    float sc = sum;
    #pragma unroll
    for (int d = 1; d < 64; d <<= 1) {
        float u = __shfl_up(sc, d);
        if (lane >= d) sc += u;
    }
    float run = sc - sum;
    #pragma unroll
    for (int j = 0; j < 4; ++j) {
        float t = v[j];
        p[(size_t)(lane * 4 + j) * 64] = run;
        run += t;
    }
}

// ---------------------------------------------------------------------------
// out-GEMM v2: K[b][h][l] = base[h] + sum_n CB[h][n] * S[n][l]
// grid (64 lt, 4 hq, 8 b) x 256 thr. Block = 64 l x 256 h.
// Phase 1: build S[64 l][64 n] in LDS from dAf + Ppre (per-stile independent).
// Phase 2: 4 waves x (4 mt x 4 lt4) frags, K=64 in 2 steps, 32 MFMA/wave.
// Phase 3: epilogue via per-wave-private LDS region -> float4 stores,
//          1 KB/instr, 256-B contiguous segments.
// ---------------------------------------------------------------------------
__global__ __launch_bounds__(256) void out_kernel(
    const float* __restrict__ dAf, const float* __restrict__ Ppre,
    const unsigned short* __restrict__ CBswz, const float* __restrict__ base,
    float* __restrict__ K)
{
    __shared__ float slds[64][65];   // 16.6 KB; S then epilogue scratch
    const int tid = threadIdx.x;
    const int lt = blockIdx.x, hq = blockIdx.y, b = blockIdx.z;
    const int l0 = lt * 64;

    // Phase 1: S for this 64-l tile (stiles independent thanks to Ppre)
    {
        const int n = tid & 63, q = tid >> 6;
        const float* dp = dAf + ((size_t)b * L_ + l0 + q * 16) * 64 + n;
        float run = Ppre[((size_t)b * 256 + lt * 4 + q) * 64 + n];
        #pragma unroll
        for (int r = 0; r < 16; ++r) {
            run += dp[(size_t)r * 64];
            slds[q * 16 + r][n] = run;
        }
    }
    __syncthreads();

    const int lane = tid & 63, w = tid >> 6;
    const int lm = lane & 15, lq = lane >> 4;

    // S B-frags: frag (kt, lt4): lane -> col l = lt4*16+lm, elem j -> n=kt*32+lq*8+j
    i32x4 sf[2][4];
    #pragma unroll
    for (int kt = 0; kt < 2; ++kt) {
        #pragma unroll
        for (int lt4 = 0; lt4 < 4; ++lt4) {
            const float* sr = &slds[lt4 * 16 + lm][kt * 32 + lq * 8];
            float x0 = sr[0], x1 = sr[1], x2 = sr[2], x3 = sr[3];
            float x4 = sr[4], x5 = sr[5], x6 = sr[6], x7 = sr[7];
            i32x4 t;
            t.x = bfpk(x0, x1); t.y = bfpk(x2, x3);
            t.z = bfpk(x4, x5); t.w = bfpk(x6, x7);
            sf[kt][lt4] = t;
        }
    }

    // acc init with base[h]
    f32x4 acc[4][4];
    #pragma unroll
    for (int m = 0; m < 4; ++m) {
        float4 bb = *(const float4*)(base + hq * 256 + w * 64 + m * 16 + lq * 4);
        f32x4 bv = f32x4{bb.x, bb.y, bb.z, bb.w};
        #pragma unroll
        for (int lt4 = 0; lt4 < 4; ++lt4) acc[m][lt4] = bv;
    }
    // GEMM
    #pragma unroll
    for (int kt = 0; kt < 2; ++kt) {
        #pragma unroll
        for (int m = 0; m < 4; ++m) {
            const int mtg = hq * 16 + w * 4 + m;
            i32x4 cb = ((const i32x4*)CBswz)[(kt * 64 + mtg) * 64 + lane];
            #pragma unroll
            for (int lt4 = 0; lt4 < 4; ++lt4)
                mfma16(acc[m][lt4], cb, sf[kt][lt4]);
        }
    }
    asm volatile("s_nop 7\n\ts_nop 7"
                 : "+v"(acc[0][0]), "+v"(acc[0][1]), "+v"(acc[0][2]), "+v"(acc[0][3]),
                   "+v"(acc[1][0]), "+v"(acc[1][1]), "+v"(acc[1][2]), "+v"(acc[1][3]),
                   "+v"(acc[2][0]), "+v"(acc[2][1]), "+v"(acc[2][2]), "+v"(acc[2][3]),
                   "+v"(acc[3][0]), "+v"(acc[3][1]), "+v"(acc[3][2]), "+v"(acc[3][3]));

    // Phase 3: epilogue. Wave-private LDS rows [w*16, w*16+16).
    __syncthreads();   // all S reads done before overwrite
    const int row4 = lane >> 4;   // 0..3
    const int seg  = lane & 15;   // 0..15
    #pragma unroll
    for (int m = 0; m < 4; ++m) {
        #pragma unroll
        for (int lt4 = 0; lt4 < 4; ++lt4)
            #pragma unroll
            for (int r = 0; r < 4; ++r)
                slds[w * 16 + lq * 4 + r][lt4 * 16 + lm] = acc[m][lt4][r];
        // same-wave DS ops are ordered; compiler inserts lgkmcnt waits for reads
        #pragma unroll
        for (int r2 = 0; r2 < 4; ++r2) {
            const int hl = r2 * 4 + row4;
            const float* sp2 = &slds[w * 16 + hl][seg * 4];
            float4 v;
            v.x = sp2[0]; v.y = sp2[1]; v.z = sp2[2]; v.w = sp2[3];
            float* kp = K + ((size_t)b * H_ + hq * 256 + w * 64 + m * 16 + hl) * (size_t)L_
                          + l0 + seg * 4;
            *(float4*)kp = v;
        }
    }
}

// ---------------------------------------------------------------------------
extern "C" void kernel_launch(void* const* d_in, const int* in_sizes, int n_in,
                              void* d_out, int out_size, void* d_ws, size_t ws_size,
                              hipStream_t stream) {
    const float* du   = (const float*)d_in[0];  // [B][H][L]
    const float* C    = (const float*)d_in[1];  // [H][N]
    const float* Bvec = (const float*)d_in[2];  // [N]
    const float* A    = (const float*)d_in[3];  // [N][N]
    const float* W    = (const float*)d_in[4];  // [N][H]
    float* K = (float*)d_out;                   // [B][H][L]

    float* dAf = (float*)d_ws;                                     // B*L*64 f32 = 8 MB
    unsigned short* Wswz  = (unsigned short*)(dAf + (size_t)B_ * L_ * 64);  // 65536 u16
    unsigned short* CBswz = Wswz + 65536;                          // 65536 u16
    float* Tsum = (float*)(CBswz + 65536);                         // 8*256*64 f32
    float* base = Tsum + (size_t)B_ * 256 * 64;                    // 1024 f32

    setup_kernel<<<68, 256, 0, stream>>>(C, Bvec, A, W, Wswz, CBswz, base);
    dA_kernel<<<dim3(64, B_), 512, 0, stream>>>(du, Wswz, dAf, Tsum);
    pscan_kernel<<<64, 512, 0, stream>>>(Tsum);
    out_kernel<<<dim3(64, 4, B_), 256, 0, stream>>>(dAf, Tsum, CBswz, base, K);
}